// Round 18
// baseline (139.095 us; speedup 1.0000x reference)
//
#include <hip/hip_runtime.h>
#include <hip/hip_bf16.h>

#define DIM 768
#define NHEADS 12
#define HD 64
#define NTOK 197
#define BATCH 64
#define NTOKENS (BATCH*NTOK)          // 12608
#define NPAIR (NTOK*NTOK)             // 38809
#define QK_SCALE_E2 0.18033688011f    // 64^-0.5 * log2(e): softmax in exp2 domain
#define LOG2E 1.44269504089f
#define CDIM 2304                     // qkv row width

typedef short bf16x8 __attribute__((ext_vector_type(8)));
typedef float f32x4 __attribute__((ext_vector_type(4)));

#define MFMA(a,b,c) __builtin_amdgcn_mfma_f32_16x16x32_bf16(a,b,c,0,0,0)

__device__ __forceinline__ unsigned short f2bf(float f) {
    union { float f; unsigned u; } v; v.f = f;
    unsigned r = v.u + 0x7FFFu + ((v.u >> 16) & 1u);
    return (unsigned short)(r >> 16);
}

__device__ __forceinline__ float bf2f(unsigned short u) {
    union { unsigned v; float f; } x; x.v = ((unsigned)u) << 16; return x.f;
}

// one-instruction 2^x (v_exp_f32); pure VALU reg dataflow, scheduler-safe
__device__ __forceinline__ float fexp2(float x) {
    float d;
    asm("v_exp_f32 %0, %1" : "=v"(d) : "v"(x));
    return d;
}

// two f32 -> packed 2x bf16 (RNE), one VALU op
__device__ __forceinline__ unsigned cvtpk(float lo, float hi) {
    unsigned d;
    asm("v_cvt_pk_bf16_f32 %0, %1, %2" : "=v"(d) : "v"(lo), "v"(hi));
    return d;
}

__device__ __forceinline__ unsigned vperm(unsigned s0, unsigned s1, unsigned sel) {
    unsigned d;
    asm("v_perm_b32 %0, %1, %2, %3" : "=v"(d) : "v"(s0), "v"(s1), "s"(sel));
    return d;
}

__device__ __forceinline__ void gload16(const unsigned short* g, unsigned short* l) {
    __builtin_amdgcn_global_load_lds(
        (const __attribute__((address_space(1))) void*)g,
        (__attribute__((address_space(3))) void*)l, 16, 0, 0);
}

// bijective XCD-aware block swizzle (m204)
__device__ __forceinline__ int xcd_swz(int orig, int nwg) {
    int q = nwg >> 3, r = nwg & 7;
    int xcd = orig & 7, idx = orig >> 3;
    return (xcd < r ? xcd * (q + 1) : r * (q + 1) + (xcd - r) * q) + idx;
}

// ---------------- fused prep: 3x fp32->bf16 convert + bias gather (bf16, *log2e)
#define NB_X 4728     // NELEM/8/256
#define NB_WQ 864     // WQKV/8/256
#define NB_WP 288     // WPROJ/8/256
#define NB_BIAS 1820  // ceil(465708/256)

__device__ __forceinline__ void cvt8(const float* __restrict__ s,
                                     unsigned short* __restrict__ d, int t, int n8) {
    if (t >= n8) return;
    float4 a = ((const float4*)s)[t * 2], b = ((const float4*)s)[t * 2 + 1];
    union { unsigned short u[8]; bf16x8 v; } p;
    p.u[0] = f2bf(a.x); p.u[1] = f2bf(a.y); p.u[2] = f2bf(a.z); p.u[3] = f2bf(a.w);
    p.u[4] = f2bf(b.x); p.u[5] = f2bf(b.y); p.u[6] = f2bf(b.z); p.u[7] = f2bf(b.w);
    ((bf16x8*)d)[t] = p.v;
}

__global__ __launch_bounds__(256) void prep(
    const float* __restrict__ x, const float* __restrict__ qw,
    const float* __restrict__ pw, const float* __restrict__ rpb,
    const int* __restrict__ rel,
    unsigned short* __restrict__ Xb, unsigned short* __restrict__ Wqb,
    unsigned short* __restrict__ Wpb, unsigned short* __restrict__ biasm)
{
    int bid = blockIdx.x;
    if (bid < NB_X) {
        cvt8(x, Xb, bid * 256 + threadIdx.x, NB_X * 256);
    } else if (bid < NB_X + NB_WQ) {
        cvt8(qw, Wqb, (bid - NB_X) * 256 + threadIdx.x, NB_WQ * 256);
    } else if (bid < NB_X + NB_WQ + NB_WP) {
        cvt8(pw, Wpb, (bid - NB_X - NB_WQ) * 256 + threadIdx.x, NB_WP * 256);
    } else {
        int t = (bid - NB_X - NB_WQ - NB_WP) * 256 + threadIdx.x;
        if (t < NHEADS * NPAIR) {
            int h = t / NPAIR, p = t - h * NPAIR;
            biasm[t] = f2bf(rpb[rel[p] * NHEADS + h] * LOG2E);
        }
    }
}

// ---------------- GEMM1: qkv[token][2304] = Xb @ Wb^T (+bias, Q pre-scaled to
// exp2 domain). 256x128 block, 4 waves, wave-tile 128x64 (0.375 LDS reads/MFMA).
__global__ __launch_bounds__(256, 2) void gemm_qkv256(
    const unsigned short* __restrict__ Xb, const unsigned short* __restrict__ Wb,
    const float* __restrict__ qbias, const float* __restrict__ vbias,
    unsigned short* __restrict__ QKVb)
{
    __shared__ __attribute__((aligned(16))) unsigned short As[256 * 64];  // 32 KB
    __shared__ __attribute__((aligned(16))) unsigned short Bs[128 * 64];  // 16 KB
    int tid = threadIdx.x, lane = tid & 63, wid = tid >> 6;
    int wg = xcd_swz(blockIdx.x, 900);
    int bx = wg / 18, by = wg % 18;           // consecutive wg share X-panel
    int m0 = bx * 256, n0 = by * 128;
    int wm = (wid >> 1) * 128, wn = (wid & 1) * 64;
    int r15 = lane & 15, hi = lane >> 4, sx = lane & 7;
    int sl0 = hi ^ sx, sl1 = (hi + 4) ^ sx;

    int slot8 = ((lane & 7) ^ (lane >> 3)) * 8;
    unsigned asrc[8];
    #pragma unroll
    for (int i = 0; i < 8; ++i) {
        int row = i * 32 + wid * 8 + (lane >> 3);
        int ar = m0 + row; if (ar >= NTOKENS) ar = NTOKENS - 1;
        asrc[i] = (unsigned)(ar * DIM + slot8);
    }
    unsigned bsrc[4];
    #pragma unroll
    for (int i = 0; i < 4; ++i) {
        int row = i * 32 + wid * 8 + (lane >> 3);
        bsrc[i] = (unsigned)((n0 + row) * DIM + slot8);
    }

    f32x4 acc[8][4];
    #pragma unroll
    for (int i = 0; i < 8; ++i)
        #pragma unroll
        for (int j = 0; j < 4; ++j) acc[i][j] = (f32x4){0.f, 0.f, 0.f, 0.f};

    for (int k0 = 0; k0 < DIM; k0 += 64) {
        __syncthreads();
        #pragma unroll
        for (int i = 0; i < 8; ++i)
            gload16(Xb + asrc[i] + k0, &As[i * 2048 + wid * 512 + lane * 8]);
        #pragma unroll
        for (int i = 0; i < 4; ++i)
            gload16(Wb + bsrc[i] + k0, &Bs[i * 2048 + wid * 512 + lane * 8]);
        __syncthreads();
        #pragma unroll
        for (int ks = 0; ks < 2; ++ks) {
            int so = (ks ? sl1 : sl0) * 8;
            bf16x8 af[8], bw[4];
            #pragma unroll
            for (int i = 0; i < 8; ++i)
                af[i] = *(const bf16x8*)&As[(wm + i * 16 + r15) * 64 + so];
            #pragma unroll
            for (int j = 0; j < 4; ++j)
                bw[j] = *(const bf16x8*)&Bs[(wn + j * 16 + r15) * 64 + so];
            __builtin_amdgcn_s_setprio(1);
            #pragma unroll
            for (int i = 0; i < 8; ++i)
                #pragma unroll
                for (int j = 0; j < 4; ++j)
                    acc[i][j] = MFMA(af[i], bw[j], acc[i][j]);
            __builtin_amdgcn_s_setprio(0);
        }
    }
    __syncthreads();          // all waves done reading As/Bs; reuse as transpose buf

    // epilogue: per-wave transpose region As[wid*4096..], two 64-row halves
    unsigned short* reg = &As[wid * 4096];
    int which = n0 / DIM;                      // block-uniform (768 = 6*128)
    float scl = (which == 0) ? QK_SCALE_E2 : 1.f;
    #pragma unroll
    for (int h = 0; h < 2; ++h) {
        #pragma unroll
        for (int j = 0; j < 4; ++j) {
            int colr = n0 - which * DIM + wn + j * 16 + r15;
            float bv = (which == 0) ? qbias[colr] : (which == 2 ? vbias[colr] : 0.f);
            #pragma unroll
            for (int mi = 0; mi < 4; ++mi) {
                #pragma unroll
                for (int r = 0; r < 4; ++r) {
                    int lr = mi * 16 + hi * 4 + r;
                    int c = j * 16 + r15;
                    reg[lr * 64 + (c ^ (((lr >> 2) & 3) << 4))] =
                        f2bf((acc[h * 4 + mi][j][r] + bv) * scl);
                }
            }
        }
        #pragma unroll
        for (int it = 0; it < 8; ++it) {
            int c = it * 64 + lane;
            int lr = c >> 3, cc = c & 7;
            int row = m0 + wm + h * 64 + lr;
            if (row < NTOKENS) {
                bf16x8 v = *(bf16x8*)&reg[lr * 64 + ((cc * 8) ^ (((lr >> 2) & 3) << 4))];
                *(bf16x8*)(QKVb + (size_t)row * CDIM + n0 + wn + cc * 8) = v;
            }
        }
    }
}

// ---------------- GEMM2: out = O @ Wp^T + proj_b (fp32 out)
__global__ __launch_bounds__(256, 2) void gemm_proj(
    const unsigned short* __restrict__ Ob, const unsigned short* __restrict__ Wp,
    const float* __restrict__ pbias, float* __restrict__ out)
{
    __shared__ __attribute__((aligned(16))) unsigned short As[128 * 64];
    __shared__ __attribute__((aligned(16))) unsigned short Bs[128 * 64];
    int tid = threadIdx.x, lane = tid & 63, wid = tid >> 6;
    int wg = xcd_swz(blockIdx.x, 594);
    int bx = wg / 6, by = wg % 6;             // consecutive wg share A-panel
    int m0 = bx * 128, n0 = by * 128;
    int wm = (wid >> 1) * 64, wn = (wid & 1) * 64;

    size_t abase[4], bbase[4];
    unsigned short *alds[4], *blds[4];
    #pragma unroll
    for (int i = 0; i < 4; ++i) {
        int chunk = i * 4 + wid;
        int row = chunk * 8 + (lane >> 3);
        int slot = (lane & 7) ^ (row & 7);
        int ar = m0 + row; if (ar >= NTOKENS) ar = NTOKENS - 1;
        abase[i] = (size_t)ar * DIM + slot * 8;
        bbase[i] = (size_t)(n0 + row) * DIM + slot * 8;
        alds[i] = &As[chunk * 512];
        blds[i] = &Bs[chunk * 512];
    }
    int r15 = lane & 15, hi = lane >> 4, sx = lane & 7;
    int s0 = (hi ^ sx) * 8, s1 = ((hi + 4) ^ sx) * 8;
    int arow[4], brow[4];
    #pragma unroll
    for (int i = 0; i < 4; ++i) {
        arow[i] = (wm + i * 16 + r15) * 64;
        brow[i] = (wn + i * 16 + r15) * 64;
    }

    f32x4 acc[4][4];
    #pragma unroll
    for (int i = 0; i < 4; ++i)
        #pragma unroll
        for (int j = 0; j < 4; ++j) acc[i][j] = (f32x4){0.f, 0.f, 0.f, 0.f};

    for (int k0 = 0; k0 < DIM; k0 += 64) {
        __syncthreads();
        #pragma unroll
        for (int i = 0; i < 4; ++i) {
            gload16(Ob + abase[i] + k0, alds[i]);
            gload16(Wp + bbase[i] + k0, blds[i]);
        }
        __syncthreads();
        #pragma unroll
        for (int ks = 0; ks < 2; ++ks) {
            int so = ks ? s1 : s0;
            bf16x8 af[4], bwv[4];
            #pragma unroll
            for (int i = 0; i < 4; ++i) af[i] = *(bf16x8*)&As[arow[i] + so];
            #pragma unroll
            for (int j = 0; j < 4; ++j) bwv[j] = *(bf16x8*)&Bs[brow[j] + so];
            __builtin_amdgcn_s_setprio(1);
            #pragma unroll
            for (int i = 0; i < 4; ++i)
                #pragma unroll
                for (int j = 0; j < 4; ++j)
                    acc[i][j] = MFMA(af[i], bwv[j], acc[i][j]);
            __builtin_amdgcn_s_setprio(0);
        }
    }

    #pragma unroll
    for (int j = 0; j < 4; ++j) {
        int col = n0 + wn + j * 16 + r15;
        float bv = pbias[col];
        #pragma unroll
        for (int i = 0; i < 4; ++i) {
            #pragma unroll
            for (int r = 0; r < 4; ++r) {
                int row = m0 + wm + i * 16 + hi * 4 + r;
                if (row < NTOKENS)
                    out[(size_t)row * DIM + col] = acc[i][j][r] + bv;
            }
        }
    }
}

// ---------------- fused attention: QKV[token][2304] in, O[token][768] out
// Barrier graph: {K-stage, VT-pack, Q, bias} -> bar1 -> QK^T -> bar2 (P/K WAR)
// -> softmax+P (wave-private) -> PV (VT ready since bar1) -> O. 2 barriers.
// qt==3 waves 1..3 cover rows >= 208 (all invalid): they stage K/V and hit the
// barriers, but skip Q/bias loads, QK^T, and the whole post-bar2 section.
#define KP 72          // Kl pitch (elems)
#define PP 232         // Pl pitch (elems), 464B rows (16B-aligned)
#define VPITCH 256     // VT pitch (elems) = 32 16B-slots

__global__ __launch_bounds__(256, 2) void attn(
    const unsigned short* __restrict__ QKV, const unsigned short* __restrict__ biasm,
    unsigned short* __restrict__ O)
{
    __shared__ __attribute__((aligned(16))) unsigned short VT[64 * VPITCH];   // 32768 B
    __shared__ __attribute__((aligned(16))) unsigned short KlPl[208 * KP];    // 29952 B

    int tid = threadIdx.x, lane = tid & 63, wid = tid >> 6;
    int r15 = lane & 15, hi = lane >> 4;
    int wg = blockIdx.x;
    int g = wg >> 5, qt = (wg >> 3) & 3, p = wg & 7;
    int bh = g * 8 + p;
    int h = bh % NHEADS, b = bh / NHEADS;
    size_t tb = (size_t)b * NTOK;
    int hq = h * 64;
    int rbase = qt * 64 + wid * 16 + hi * 4;
    bool act = (qt < 3) || (wid == 0);        // wave-uniform: has >=1 valid row

    // (a) K loads first -> K ds_writes wait only on K (V/Q/bias stay in flight)
    int kcol = (tid & 7) * 8;
    bf16x8 kreg[7];
    #pragma unroll
    for (int t = 0; t < 7; ++t) {
        int row = t * 32 + (tid >> 3);
        int rc = row < NTOK ? row : (NTOK - 1);
        kreg[t] = *(const bf16x8*)(QKV + (tb + rc) * CDIM + 768 + hq + kcol);
    }

    // (b) V loads into regs
    bf16x8 v0r[4], v1r[4];
    #pragma unroll
    for (int it = 0; it < 4; ++it) {
        int c = it * 256 + tid;
        int rp = c >> 3, kc = c & 7;
        int r0 = 2 * rp, r1 = 2 * rp + 1;
        bf16x8 z = (bf16x8)(short)0;
        v0r[it] = z; v1r[it] = z;
        if (r0 < NTOK) v0r[it] = *(const bf16x8*)(QKV + (tb + r0) * CDIM + 1536 + hq + kc * 8);
        if (r1 < NTOK) v1r[it] = *(const bf16x8*)(QKV + (tb + r1) * CDIM + 1536 + hq + kc * 8);
    }

    // (c) Q fragments + (d) bias prefetch — only for waves with valid rows
    bf16x8 aq[2];
    unsigned short breg[4][13];
    if (act) {
        int qrow_g = qt * 64 + wid * 16 + r15;
        int qsrc = qrow_g < NTOK ? qrow_g : (NTOK - 1);
        #pragma unroll
        for (int ks = 0; ks < 2; ++ks)
            aq[ks] = *(const bf16x8*)(QKV + (tb + qsrc) * CDIM + hq + ks * 32 + hi * 8);
        const unsigned short* bb = biasm + h * NPAIR;
        #pragma unroll
        for (int r = 0; r < 4; ++r) {
            int row_g = rbase + r;
            int rowc = row_g < NTOK ? row_g : (NTOK - 1);
            const unsigned short* brow = bb + rowc * NTOK + r15;
            #pragma unroll
            for (int t = 0; t < 13; ++t) {
                int off = t * 16;
                if (t == 12 && r15 >= 5) off = 0;
                breg[r][t] = brow[off];
            }
        }
    }

    // K regs -> LDS
    #pragma unroll
    for (int t = 0; t < 7; ++t) {
        int row = t * 32 + (tid >> 3);
        if (row < NTOK)
            *(bf16x8*)&KlPl[row * KP + kcol] = kreg[t];
    }

    // V regs -> VT (swizzled) BEFORE bar1: pack VALU overlaps load latency;
    // bar1 then covers both K and VT visibility -> no barrier before PV later.
    #pragma unroll
    for (int it = 0; it < 4; ++it) {
        int c = it * 256 + tid;
        int rp = c >> 3, kc = c & 7;
        if (rp < 112) {
            union { bf16x8 v; unsigned u[4]; } a0, a1;
            a0.v = v0r[it]; a1.v = v1r[it];
            #pragma unroll
            for (int rr = 0; rr < 4; ++rr) {
                unsigned we = vperm(a1.u[rr], a0.u[rr], 0x05040100u);   // j = 2rr
                unsigned wo = vperm(a1.u[rr], a0.u[rr], 0x07060302u);   // j = 2rr+1
                int j0 = 2 * rr, j1 = 2 * rr + 1;
                int s20 = (rp >> 2) ^ j0 ^ kc;
                int s21 = (rp >> 2) ^ j1 ^ kc;
                *(unsigned*)&VT[(kc * 8 + j0) * VPITCH + s20 * 8 + (rp & 3) * 2] = we;
                *(unsigned*)&VT[(kc * 8 + j1) * VPITCH + s21 * 8 + (rp & 3) * 2] = wo;
            }
        }
    }
    __syncthreads();          // bar1: K + VT staged

    // S' = (Q*log2e*scale) K^T  -> scores already in exp2 domain
    f32x4 sa[13];
    if (act) {
        #pragma unroll
        for (int t = 0; t < 13; ++t) sa[t] = (f32x4){0.f,0.f,0.f,0.f};
        __builtin_amdgcn_s_setprio(1);
        #pragma unroll
        for (int t = 0; t < 13; ++t) {
            #pragma unroll
            for (int ks = 0; ks < 2; ++ks) {
                bf16x8 bk = *(bf16x8*)&KlPl[(t * 16 + r15) * KP + ks * 32 + hi * 8];
                sa[t] = MFMA(aq[ks], bk, sa[t]);
            }
        }
        __builtin_amdgcn_s_setprio(0);
    }
    __syncthreads();          // bar2: all waves past QK^T; Kl region becomes Pl

    if (!act) return;         // no barriers after this point

    // softmax in exp2 domain (unnormalized; 1/sum deferred) -> P into KlPl
    int plbase = wid * (16 * PP);
    float invr[4];
    #pragma unroll
    for (int r = 0; r < 4; ++r) {
        #pragma unroll
        for (int t = 0; t < 13; ++t) {
            int col = t * 16 + r15;
            if (col < NTOK) sa[t][r] += bf2f(breg[r][t]);
            else            sa[t][r] = -1e30f;
        }
        // balanced max tree (depth 4)
        float m0a = fmaxf(fmaxf(sa[0][r], sa[1][r]), fmaxf(sa[2][r], sa[3][r]));
        float m1a = fmaxf(fmaxf(sa[4][r], sa[5][r]), fmaxf(sa[6][r], sa[7][r]));
        float m2a = fmaxf(fmaxf(sa[8][r], sa[9][r]), fmaxf(sa[10][r], sa[11][r]));
        float mx = fmaxf(fmaxf(m0a, m1a), fmaxf(m2a, sa[12][r]));
        #pragma unroll
        for (int m = 1; m < 16; m <<= 1) mx = fmaxf(mx, __shfl_xor(mx, m));
        #pragma unroll
        for (int t = 0; t < 13; ++t)
            sa[t][r] = fexp2(sa[t][r] - mx);
        // balanced sum tree
        float s0a = (sa[0][r] + sa[1][r]) + (sa[2][r] + sa[3][r]);
        float s1a = (sa[4][r] + sa[5][r]) + (sa[6][r] + sa[7][r]);
        float s2a = (sa[8][r] + sa[9][r]) + (sa[10][r] + sa[11][r]);
        float sum = (s0a + s1a) + (s2a + sa[12][r]);
        int roff = plbase + (hi * 4 + r) * PP;
        #pragma unroll
        for (int tp = 0; tp < 6; ++tp) {
            unsigned u = cvtpk(sa[2 * tp][r], sa[2 * tp + 1][r]);
            KlPl[roff + (2 * tp) * 16 + r15] = (unsigned short)u;
            KlPl[roff + (2 * tp + 1) * 16 + r15] = (unsigned short)(u >> 16);
        }
        KlPl[roff + 192 + r15] = f2bf(sa[12][r]);
        KlPl[roff + 208 + r15] = 0;
        #pragma unroll
        for (int m = 1; m < 16; m <<= 1) sum += __shfl_xor(sum, m);
        invr[r] = __builtin_amdgcn_rcpf(sum);
    }
    // NO barrier: P region is wave-private (in-wave DS ordering); VT ready since bar1

    // O = P V
    f32x4 oa[4];
    #pragma unroll
    for (int dt = 0; dt < 4; ++dt) oa[dt] = (f32x4){0.f,0.f,0.f,0.f};
    int X = hi ^ (r15 & 7) ^ (r15 >> 3);
    __builtin_amdgcn_s_setprio(1);
    #pragma unroll
    for (int ks = 0; ks < 7; ++ks) {
        bf16x8 ap = *(bf16x8*)&KlPl[plbase + r15 * PP + ks * 32 + hi * 8];
        #pragma unroll
        for (int dt = 0; dt < 4; ++dt) {
            int d = dt * 16 + r15;
            int slotp = (ks * 4) ^ (dt * 2) ^ X;
            bf16x8 bv = *(bf16x8*)&VT[d * VPITCH + slotp * 8];
            oa[dt] = MFMA(ap, bv, oa[dt]);
        }
    }
    __builtin_amdgcn_s_setprio(0);

    // O write: scale by 1/sum (cvt_pk pairs), per-wave LDS transpose -> 16B stores
    #pragma unroll
    for (int r = 0; r < 4; ++r) {
        int roff = plbase + (hi * 4 + r) * 72;
        #pragma unroll
        for (int dp = 0; dp < 2; ++dp) {
            unsigned u = cvtpk(oa[2 * dp][r] * invr[r], oa[2 * dp + 1][r] * invr[r]);
            KlPl[roff + (2 * dp) * 16 + r15] = (unsigned short)u;
            KlPl[roff + (2 * dp + 1) * 16 + r15] = (unsigned short)(u >> 16);
        }
    }
    #pragma unroll
    for (int it = 0; it < 2; ++it) {
        int c = it * 64 + lane;
        int lr = c >> 3, cc = c & 7;
        int qrow = qt * 64 + wid * 16 + lr;
        if (qrow < NTOK)
            *(bf16x8*)(O + (tb + qrow) * DIM + hq + cc * 8) =
                *(bf16x8*)&KlPl[plbase + lr * 72 + cc * 8];
    }
}

extern "C" void kernel_launch(void* const* d_in, const int* in_sizes, int n_in,
                              void* d_out, int out_size, void* d_ws, size_t ws_size,
                              hipStream_t stream) {
    const float* x      = (const float*)d_in[0];
    const float* qkv_w  = (const float*)d_in[1];
    const float* q_bias = (const float*)d_in[2];
    const float* v_bias = (const float*)d_in[3];
    const float* rpb    = (const float*)d_in[4];
    const float* proj_w = (const float*)d_in[5];
    const float* proj_b = (const float*)d_in[6];
    const int*   rel    = (const int*)d_in[7];
    float* out = (float*)d_out;

    const size_t NELEM = (size_t)NTOKENS * DIM;      // 9,682,944
    const size_t WQKV  = (size_t)3 * DIM * DIM;
    const size_t WPROJ = (size_t)DIM * DIM;
    unsigned short* Xb   = (unsigned short*)d_ws;    // reused as Ob after gemm_qkv
    unsigned short* Wqb  = Xb + NELEM;
    unsigned short* Wpb  = Wqb + WQKV;
    unsigned short* QKVb = Wpb + WPROJ;              // [12608][2304]
    unsigned short* biasm = QKVb + (size_t)NTOKENS * CDIM;   // bf16 [12][197][197]
    unsigned short* Ob = Xb;

    prep<<<NB_X + NB_WQ + NB_WP + NB_BIAS, 256, 0, stream>>>(
        x, qkv_w, proj_w, rpb, rel, Xb, Wqb, Wpb, biasm);

    gemm_qkv256<<<900, 256, 0, stream>>>(Xb, Wqb, q_bias, v_bias, QKVb);

    attn<<<3072, 256, 0, stream>>>(QKVb, biasm, Ob);

    gemm_proj<<<594, 256, 0, stream>>>(Ob, Wpb, proj_b, out);
}

// Round 19
// 137.106 us; speedup vs baseline: 1.0145x; 1.0145x over previous
//
#include <hip/hip_runtime.h>
#include <hip/hip_bf16.h>

#define DIM 768
#define NHEADS 12
#define HD 64
#define NTOK 197
#define BATCH 64
#define NTOKENS (BATCH*NTOK)          // 12608
#define NPAIR (NTOK*NTOK)             // 38809
#define QK_SCALE_E2 0.18033688011f    // 64^-0.5 * log2(e): softmax in exp2 domain
#define LOG2E 1.44269504089f
#define CDIM 2304                     // qkv row width

typedef short bf16x8 __attribute__((ext_vector_type(8)));
typedef float f32x4 __attribute__((ext_vector_type(4)));

#define MFMA(a,b,c) __builtin_amdgcn_mfma_f32_16x16x32_bf16(a,b,c,0,0,0)

__device__ __forceinline__ unsigned short f2bf(float f) {
    union { float f; unsigned u; } v; v.f = f;
    unsigned r = v.u + 0x7FFFu + ((v.u >> 16) & 1u);
    return (unsigned short)(r >> 16);
}

__device__ __forceinline__ float bf2f(unsigned short u) {
    union { unsigned v; float f; } x; x.v = ((unsigned)u) << 16; return x.f;
}

// one-instruction 2^x (v_exp_f32); pure VALU reg dataflow, scheduler-safe
__device__ __forceinline__ float fexp2(float x) {
    float d;
    asm("v_exp_f32 %0, %1" : "=v"(d) : "v"(x));
    return d;
}

// two f32 -> packed 2x bf16 (RNE), one VALU op
__device__ __forceinline__ unsigned cvtpk(float lo, float hi) {
    unsigned d;
    asm("v_cvt_pk_bf16_f32 %0, %1, %2" : "=v"(d) : "v"(lo), "v"(hi));
    return d;
}

__device__ __forceinline__ unsigned vperm(unsigned s0, unsigned s1, unsigned sel) {
    unsigned d;
    asm("v_perm_b32 %0, %1, %2, %3" : "=v"(d) : "v"(s0), "v"(s1), "s"(sel));
    return d;
}

__device__ __forceinline__ void gload16(const unsigned short* g, unsigned short* l) {
    __builtin_amdgcn_global_load_lds(
        (const __attribute__((address_space(1))) void*)g,
        (__attribute__((address_space(3))) void*)l, 16, 0, 0);
}

// bijective XCD-aware block swizzle (m204)
__device__ __forceinline__ int xcd_swz(int orig, int nwg) {
    int q = nwg >> 3, r = nwg & 7;
    int xcd = orig & 7, idx = orig >> 3;
    return (xcd < r ? xcd * (q + 1) : r * (q + 1) + (xcd - r) * q) + idx;
}

// ---------------- fused prep: 3x fp32->bf16 convert + bias gather (bf16, *log2e)
#define NB_X 4728     // NELEM/8/256
#define NB_WQ 864     // WQKV/8/256
#define NB_WP 288     // WPROJ/8/256
#define NB_BIAS 1820  // ceil(465708/256)

__device__ __forceinline__ void cvt8(const float* __restrict__ s,
                                     unsigned short* __restrict__ d, int t, int n8) {
    if (t >= n8) return;
    float4 a = ((const float4*)s)[t * 2], b = ((const float4*)s)[t * 2 + 1];
    union { unsigned short u[8]; bf16x8 v; } p;
    p.u[0] = f2bf(a.x); p.u[1] = f2bf(a.y); p.u[2] = f2bf(a.z); p.u[3] = f2bf(a.w);
    p.u[4] = f2bf(b.x); p.u[5] = f2bf(b.y); p.u[6] = f2bf(b.z); p.u[7] = f2bf(b.w);
    ((bf16x8*)d)[t] = p.v;
}

__global__ __launch_bounds__(256) void prep(
    const float* __restrict__ x, const float* __restrict__ qw,
    const float* __restrict__ pw, const float* __restrict__ rpb,
    const int* __restrict__ rel,
    unsigned short* __restrict__ Xb, unsigned short* __restrict__ Wqb,
    unsigned short* __restrict__ Wpb, unsigned short* __restrict__ biasm)
{
    int bid = blockIdx.x;
    if (bid < NB_X) {
        cvt8(x, Xb, bid * 256 + threadIdx.x, NB_X * 256);
    } else if (bid < NB_X + NB_WQ) {
        cvt8(qw, Wqb, (bid - NB_X) * 256 + threadIdx.x, NB_WQ * 256);
    } else if (bid < NB_X + NB_WQ + NB_WP) {
        cvt8(pw, Wpb, (bid - NB_X - NB_WQ) * 256 + threadIdx.x, NB_WP * 256);
    } else {
        int t = (bid - NB_X - NB_WQ - NB_WP) * 256 + threadIdx.x;
        if (t < NHEADS * NPAIR) {
            int h = t / NPAIR, p = t - h * NPAIR;
            biasm[t] = f2bf(rpb[rel[p] * NHEADS + h] * LOG2E);
        }
    }
}

// ---------------- GEMM1: qkv[token][2304] = Xb @ Wb^T (+bias, Q pre-scaled to
// exp2 domain). 256x128 block, 4 waves, wave-tile 128x64 (0.375 LDS reads/MFMA).
__global__ __launch_bounds__(256, 2) void gemm_qkv256(
    const unsigned short* __restrict__ Xb, const unsigned short* __restrict__ Wb,
    const float* __restrict__ qbias, const float* __restrict__ vbias,
    unsigned short* __restrict__ QKVb)
{
    __shared__ __attribute__((aligned(16))) unsigned short As[256 * 64];  // 32 KB
    __shared__ __attribute__((aligned(16))) unsigned short Bs[128 * 64];  // 16 KB
    int tid = threadIdx.x, lane = tid & 63, wid = tid >> 6;
    int wg = xcd_swz(blockIdx.x, 900);
    int bx = wg / 18, by = wg % 18;           // consecutive wg share X-panel
    int m0 = bx * 256, n0 = by * 128;
    int wm = (wid >> 1) * 128, wn = (wid & 1) * 64;
    int r15 = lane & 15, hi = lane >> 4, sx = lane & 7;
    int sl0 = hi ^ sx, sl1 = (hi + 4) ^ sx;

    int slot8 = ((lane & 7) ^ (lane >> 3)) * 8;
    unsigned asrc[8];
    #pragma unroll
    for (int i = 0; i < 8; ++i) {
        int row = i * 32 + wid * 8 + (lane >> 3);
        int ar = m0 + row; if (ar >= NTOKENS) ar = NTOKENS - 1;
        asrc[i] = (unsigned)(ar * DIM + slot8);
    }
    unsigned bsrc[4];
    #pragma unroll
    for (int i = 0; i < 4; ++i) {
        int row = i * 32 + wid * 8 + (lane >> 3);
        bsrc[i] = (unsigned)((n0 + row) * DIM + slot8);
    }

    f32x4 acc[8][4];
    #pragma unroll
    for (int i = 0; i < 8; ++i)
        #pragma unroll
        for (int j = 0; j < 4; ++j) acc[i][j] = (f32x4){0.f, 0.f, 0.f, 0.f};

    for (int k0 = 0; k0 < DIM; k0 += 64) {
        __syncthreads();
        #pragma unroll
        for (int i = 0; i < 8; ++i)
            gload16(Xb + asrc[i] + k0, &As[i * 2048 + wid * 512 + lane * 8]);
        #pragma unroll
        for (int i = 0; i < 4; ++i)
            gload16(Wb + bsrc[i] + k0, &Bs[i * 2048 + wid * 512 + lane * 8]);
        __syncthreads();
        #pragma unroll
        for (int ks = 0; ks < 2; ++ks) {
            int so = (ks ? sl1 : sl0) * 8;
            bf16x8 af[8], bw[4];
            #pragma unroll
            for (int i = 0; i < 8; ++i)
                af[i] = *(const bf16x8*)&As[(wm + i * 16 + r15) * 64 + so];
            #pragma unroll
            for (int j = 0; j < 4; ++j)
                bw[j] = *(const bf16x8*)&Bs[(wn + j * 16 + r15) * 64 + so];
            __builtin_amdgcn_s_setprio(1);
            #pragma unroll
            for (int i = 0; i < 8; ++i)
                #pragma unroll
                for (int j = 0; j < 4; ++j)
                    acc[i][j] = MFMA(af[i], bw[j], acc[i][j]);
            __builtin_amdgcn_s_setprio(0);
        }
    }
    __syncthreads();          // all waves done reading As/Bs; reuse as transpose buf

    // epilogue: per-wave transpose region As[wid*4096..], two 64-row halves
    unsigned short* reg = &As[wid * 4096];
    int which = n0 / DIM;                      // block-uniform (768 = 6*128)
    float scl = (which == 0) ? QK_SCALE_E2 : 1.f;
    #pragma unroll
    for (int h = 0; h < 2; ++h) {
        #pragma unroll
        for (int j = 0; j < 4; ++j) {
            int colr = n0 - which * DIM + wn + j * 16 + r15;
            float bv = (which == 0) ? qbias[colr] : (which == 2 ? vbias[colr] : 0.f);
            #pragma unroll
            for (int mi = 0; mi < 4; ++mi) {
                #pragma unroll
                for (int r = 0; r < 4; ++r) {
                    int lr = mi * 16 + hi * 4 + r;
                    int c = j * 16 + r15;
                    reg[lr * 64 + (c ^ (((lr >> 2) & 3) << 4))] =
                        f2bf((acc[h * 4 + mi][j][r] + bv) * scl);
                }
            }
        }
        #pragma unroll
        for (int it = 0; it < 8; ++it) {
            int c = it * 64 + lane;
            int lr = c >> 3, cc = c & 7;
            int row = m0 + wm + h * 64 + lr;
            if (row < NTOKENS) {
                bf16x8 v = *(bf16x8*)&reg[lr * 64 + ((cc * 8) ^ (((lr >> 2) & 3) << 4))];
                *(bf16x8*)(QKVb + (size_t)row * CDIM + n0 + wn + cc * 8) = v;
            }
        }
    }
}

// ---------------- GEMM2: out = O @ Wp^T + proj_b (fp32 out)
__global__ __launch_bounds__(256, 2) void gemm_proj(
    const unsigned short* __restrict__ Ob, const unsigned short* __restrict__ Wp,
    const float* __restrict__ pbias, float* __restrict__ out)
{
    __shared__ __attribute__((aligned(16))) unsigned short As[128 * 64];
    __shared__ __attribute__((aligned(16))) unsigned short Bs[128 * 64];
    int tid = threadIdx.x, lane = tid & 63, wid = tid >> 6;
    int wg = xcd_swz(blockIdx.x, 594);
    int bx = wg / 6, by = wg % 6;             // consecutive wg share A-panel
    int m0 = bx * 128, n0 = by * 128;
    int wm = (wid >> 1) * 64, wn = (wid & 1) * 64;

    size_t abase[4], bbase[4];
    unsigned short *alds[4], *blds[4];
    #pragma unroll
    for (int i = 0; i < 4; ++i) {
        int chunk = i * 4 + wid;
        int row = chunk * 8 + (lane >> 3);
        int slot = (lane & 7) ^ (row & 7);
        int ar = m0 + row; if (ar >= NTOKENS) ar = NTOKENS - 1;
        abase[i] = (size_t)ar * DIM + slot * 8;
        bbase[i] = (size_t)(n0 + row) * DIM + slot * 8;
        alds[i] = &As[chunk * 512];
        blds[i] = &Bs[chunk * 512];
    }
    int r15 = lane & 15, hi = lane >> 4, sx = lane & 7;
    int s0 = (hi ^ sx) * 8, s1 = ((hi + 4) ^ sx) * 8;
    int arow[4], brow[4];
    #pragma unroll
    for (int i = 0; i < 4; ++i) {
        arow[i] = (wm + i * 16 + r15) * 64;
        brow[i] = (wn + i * 16 + r15) * 64;
    }

    f32x4 acc[4][4];
    #pragma unroll
    for (int i = 0; i < 4; ++i)
        #pragma unroll
        for (int j = 0; j < 4; ++j) acc[i][j] = (f32x4){0.f, 0.f, 0.f, 0.f};

    for (int k0 = 0; k0 < DIM; k0 += 64) {
        __syncthreads();
        #pragma unroll
        for (int i = 0; i < 4; ++i) {
            gload16(Ob + abase[i] + k0, alds[i]);
            gload16(Wp + bbase[i] + k0, blds[i]);
        }
        __syncthreads();
        #pragma unroll
        for (int ks = 0; ks < 2; ++ks) {
            int so = ks ? s1 : s0;
            bf16x8 af[4], bwv[4];
            #pragma unroll
            for (int i = 0; i < 4; ++i) af[i] = *(bf16x8*)&As[arow[i] + so];
            #pragma unroll
            for (int j = 0; j < 4; ++j) bwv[j] = *(bf16x8*)&Bs[brow[j] + so];
            __builtin_amdgcn_s_setprio(1);
            #pragma unroll
            for (int i = 0; i < 4; ++i)
                #pragma unroll
                for (int j = 0; j < 4; ++j)
                    acc[i][j] = MFMA(af[i], bwv[j], acc[i][j]);
            __builtin_amdgcn_s_setprio(0);
        }
    }

    #pragma unroll
    for (int j = 0; j < 4; ++j) {
        int col = n0 + wn + j * 16 + r15;
        float bv = pbias[col];
        #pragma unroll
        for (int i = 0; i < 4; ++i) {
            #pragma unroll
            for (int r = 0; r < 4; ++r) {
                int row = m0 + wm + i * 16 + hi * 4 + r;
                if (row < NTOKENS)
                    out[(size_t)row * DIM + col] = acc[i][j][r] + bv;
            }
        }
    }
}

// ---------------- fused attention: QKV[token][2304] in, O[token][768] out
// Barrier graph: {K-stage, VT-pack, Q, bias} -> bar1 -> QK^T -> bar2 (P/K WAR)
// -> softmax+P (wave-private) -> PV (VT ready since bar1) -> O. 2 barriers.
#define KP 72          // Kl pitch (elems)
#define PP 232         // Pl pitch (elems), 464B rows (16B-aligned)
#define VPITCH 256     // VT pitch (elems) = 32 16B-slots

__global__ __launch_bounds__(256, 2) void attn(
    const unsigned short* __restrict__ QKV, const unsigned short* __restrict__ biasm,
    unsigned short* __restrict__ O)
{
    __shared__ __attribute__((aligned(16))) unsigned short VT[64 * VPITCH];   // 32768 B
    __shared__ __attribute__((aligned(16))) unsigned short KlPl[208 * KP];    // 29952 B

    int tid = threadIdx.x, lane = tid & 63, wid = tid >> 6;
    int r15 = lane & 15, hi = lane >> 4;
    int wg = blockIdx.x;
    int g = wg >> 5, qt = (wg >> 3) & 3, p = wg & 7;
    int bh = g * 8 + p;
    int h = bh % NHEADS, b = bh / NHEADS;
    size_t tb = (size_t)b * NTOK;
    int hq = h * 64;
    int rbase = qt * 64 + wid * 16 + hi * 4;

    // (a) K loads first -> K ds_writes wait only on K (V/Q/bias stay in flight)
    int kcol = (tid & 7) * 8;
    bf16x8 kreg[7];
    #pragma unroll
    for (int t = 0; t < 7; ++t) {
        int row = t * 32 + (tid >> 3);
        int rc = row < NTOK ? row : (NTOK - 1);
        kreg[t] = *(const bf16x8*)(QKV + (tb + rc) * CDIM + 768 + hq + kcol);
    }

    // (b) V loads into regs
    bf16x8 v0r[4], v1r[4];
    #pragma unroll
    for (int it = 0; it < 4; ++it) {
        int c = it * 256 + tid;
        int rp = c >> 3, kc = c & 7;
        int r0 = 2 * rp, r1 = 2 * rp + 1;
        bf16x8 z = (bf16x8)(short)0;
        v0r[it] = z; v1r[it] = z;
        if (r0 < NTOK) v0r[it] = *(const bf16x8*)(QKV + (tb + r0) * CDIM + 1536 + hq + kc * 8);
        if (r1 < NTOK) v1r[it] = *(const bf16x8*)(QKV + (tb + r1) * CDIM + 1536 + hq + kc * 8);
    }

    // (c) Q fragments
    int qrow_g = qt * 64 + wid * 16 + r15;
    int qsrc = qrow_g < NTOK ? qrow_g : (NTOK - 1);
    bf16x8 aq[2];
    #pragma unroll
    for (int ks = 0; ks < 2; ++ks)
        aq[ks] = *(const bf16x8*)(QKV + (tb + qsrc) * CDIM + hq + ks * 32 + hi * 8);

    // (d) bias prefetch (bf16, already *log2e; consumed in softmax)
    unsigned short breg[4][13];
    {
        const unsigned short* bb = biasm + h * NPAIR;
        #pragma unroll
        for (int r = 0; r < 4; ++r) {
            int row_g = rbase + r;
            int rowc = row_g < NTOK ? row_g : (NTOK - 1);
            const unsigned short* brow = bb + rowc * NTOK + r15;
            #pragma unroll
            for (int t = 0; t < 13; ++t) {
                int off = t * 16;
                if (t == 12 && r15 >= 5) off = 0;
                breg[r][t] = brow[off];
            }
        }
    }

    // K regs -> LDS
    #pragma unroll
    for (int t = 0; t < 7; ++t) {
        int row = t * 32 + (tid >> 3);
        if (row < NTOK)
            *(bf16x8*)&KlPl[row * KP + kcol] = kreg[t];
    }

    // V regs -> VT (swizzled) BEFORE bar1: pack VALU overlaps load latency;
    // bar1 then covers both K and VT visibility -> no barrier before PV later.
    #pragma unroll
    for (int it = 0; it < 4; ++it) {
        int c = it * 256 + tid;
        int rp = c >> 3, kc = c & 7;
        if (rp < 112) {
            union { bf16x8 v; unsigned u[4]; } a0, a1;
            a0.v = v0r[it]; a1.v = v1r[it];
            #pragma unroll
            for (int rr = 0; rr < 4; ++rr) {
                unsigned we = vperm(a1.u[rr], a0.u[rr], 0x05040100u);   // j = 2rr
                unsigned wo = vperm(a1.u[rr], a0.u[rr], 0x07060302u);   // j = 2rr+1
                int j0 = 2 * rr, j1 = 2 * rr + 1;
                int s20 = (rp >> 2) ^ j0 ^ kc;
                int s21 = (rp >> 2) ^ j1 ^ kc;
                *(unsigned*)&VT[(kc * 8 + j0) * VPITCH + s20 * 8 + (rp & 3) * 2] = we;
                *(unsigned*)&VT[(kc * 8 + j1) * VPITCH + s21 * 8 + (rp & 3) * 2] = wo;
            }
        }
    }
    __syncthreads();          // bar1: K + VT staged

    // S' = (Q*log2e*scale) K^T  -> scores already in exp2 domain
    f32x4 sa[13];
    #pragma unroll
    for (int t = 0; t < 13; ++t) sa[t] = (f32x4){0.f,0.f,0.f,0.f};
    __builtin_amdgcn_s_setprio(1);
    #pragma unroll
    for (int t = 0; t < 13; ++t) {
        #pragma unroll
        for (int ks = 0; ks < 2; ++ks) {
            bf16x8 bk = *(bf16x8*)&KlPl[(t * 16 + r15) * KP + ks * 32 + hi * 8];
            sa[t] = MFMA(aq[ks], bk, sa[t]);
        }
    }
    __builtin_amdgcn_s_setprio(0);
    __syncthreads();          // bar2: all waves past QK^T; Kl region becomes Pl

    // softmax in exp2 domain (unnormalized; 1/sum deferred) -> P into KlPl
    int plbase = wid * (16 * PP);
    float invr[4];
    #pragma unroll
    for (int r = 0; r < 4; ++r) {
        #pragma unroll
        for (int t = 0; t < 13; ++t) {
            int col = t * 16 + r15;
            if (col < NTOK) sa[t][r] += bf2f(breg[r][t]);
            else            sa[t][r] = -1e30f;
        }
        // balanced max tree (depth 4)
        float m0a = fmaxf(fmaxf(sa[0][r], sa[1][r]), fmaxf(sa[2][r], sa[3][r]));
        float m1a = fmaxf(fmaxf(sa[4][r], sa[5][r]), fmaxf(sa[6][r], sa[7][r]));
        float m2a = fmaxf(fmaxf(sa[8][r], sa[9][r]), fmaxf(sa[10][r], sa[11][r]));
        float mx = fmaxf(fmaxf(m0a, m1a), fmaxf(m2a, sa[12][r]));
        #pragma unroll
        for (int m = 1; m < 16; m <<= 1) mx = fmaxf(mx, __shfl_xor(mx, m));
        #pragma unroll
        for (int t = 0; t < 13; ++t)
            sa[t][r] = fexp2(sa[t][r] - mx);
        // balanced sum tree
        float s0a = (sa[0][r] + sa[1][r]) + (sa[2][r] + sa[3][r]);
        float s1a = (sa[4][r] + sa[5][r]) + (sa[6][r] + sa[7][r]);
        float s2a = (sa[8][r] + sa[9][r]) + (sa[10][r] + sa[11][r]);
        float sum = (s0a + s1a) + (s2a + sa[12][r]);
        int roff = plbase + (hi * 4 + r) * PP;
        #pragma unroll
        for (int tp = 0; tp < 6; ++tp) {
            unsigned u = cvtpk(sa[2 * tp][r], sa[2 * tp + 1][r]);
            KlPl[roff + (2 * tp) * 16 + r15] = (unsigned short)u;
            KlPl[roff + (2 * tp + 1) * 16 + r15] = (unsigned short)(u >> 16);
        }
        KlPl[roff + 192 + r15] = f2bf(sa[12][r]);
        KlPl[roff + 208 + r15] = 0;
        #pragma unroll
        for (int m = 1; m < 16; m <<= 1) sum += __shfl_xor(sum, m);
        invr[r] = __builtin_amdgcn_rcpf(sum);
    }
    // NO barrier: P region is wave-private (in-wave DS ordering); VT ready since bar1

    // O = P V
    f32x4 oa[4];
    #pragma unroll
    for (int dt = 0; dt < 4; ++dt) oa[dt] = (f32x4){0.f,0.f,0.f,0.f};
    int X = hi ^ (r15 & 7) ^ (r15 >> 3);
    __builtin_amdgcn_s_setprio(1);
    #pragma unroll
    for (int ks = 0; ks < 7; ++ks) {
        bf16x8 ap = *(bf16x8*)&KlPl[plbase + r15 * PP + ks * 32 + hi * 8];
        #pragma unroll
        for (int dt = 0; dt < 4; ++dt) {
            int d = dt * 16 + r15;
            int slotp = (ks * 4) ^ (dt * 2) ^ X;
            bf16x8 bv = *(bf16x8*)&VT[d * VPITCH + slotp * 8];
            oa[dt] = MFMA(ap, bv, oa[dt]);
        }
    }
    __builtin_amdgcn_s_setprio(0);

    // O write: scale by 1/sum (cvt_pk pairs), per-wave LDS transpose -> 16B stores
    #pragma unroll
    for (int r = 0; r < 4; ++r) {
        int roff = plbase + (hi * 4 + r) * 72;
        #pragma unroll
        for (int dp = 0; dp < 2; ++dp) {
            unsigned u = cvtpk(oa[2 * dp][r] * invr[r], oa[2 * dp + 1][r] * invr[r]);
            KlPl[roff + (2 * dp) * 16 + r15] = (unsigned short)u;
            KlPl[roff + (2 * dp + 1) * 16 + r15] = (unsigned short)(u >> 16);
        }
    }
    #pragma unroll
    for (int it = 0; it < 2; ++it) {
        int c = it * 64 + lane;
        int lr = c >> 3, cc = c & 7;
        int qrow = qt * 64 + wid * 16 + lr;
        if (qrow < NTOK)
            *(bf16x8*)(O + (tb + qrow) * DIM + hq + cc * 8) =
                *(bf16x8*)&KlPl[plbase + lr * 72 + cc * 8];
    }
}

extern "C" void kernel_launch(void* const* d_in, const int* in_sizes, int n_in,
                              void* d_out, int out_size, void* d_ws, size_t ws_size,
                              hipStream_t stream) {
    const float* x      = (const float*)d_in[0];
    const float* qkv_w  = (const float*)d_in[1];
    const float* q_bias = (const float*)d_in[2];
    const float* v_bias = (const float*)d_in[3];
    const float* rpb    = (const float*)d_in[4];
    const float* proj_w = (const float*)d_in[5];
    const float* proj_b = (const float*)d_in[6];
    const int*   rel    = (const int*)d_in[7];
    float* out = (float*)d_out;

    const size_t NELEM = (size_t)NTOKENS * DIM;      // 9,682,944
    const size_t WQKV  = (size_t)3 * DIM * DIM;
    const size_t WPROJ = (size_t)DIM * DIM;
    unsigned short* Xb   = (unsigned short*)d_ws;    // reused as Ob after gemm_qkv
    unsigned short* Wqb  = Xb + NELEM;
    unsigned short* Wpb  = Wqb + WQKV;
    unsigned short* QKVb = Wpb + WPROJ;              // [12608][2304]
    unsigned short* biasm = QKVb + (size_t)NTOKENS * CDIM;   // bf16 [12][197][197]
    unsigned short* Ob = Xb;

    prep<<<NB_X + NB_WQ + NB_WP + NB_BIAS, 256, 0, stream>>>(
        x, qkv_w, proj_w, rpb, rel, Xb, Wqb, Wpb, biasm);

    gemm_qkv256<<<900, 256, 0, stream>>>(Xb, Wqb, q_bias, v_bias, QKVb);

    attn<<<3072, 256, 0, stream>>>(QKVb, biasm, Ob);

    gemm_proj<<<594, 256, 0, stream>>>(Ob, Wpb, proj_b, out);
}